// Round 9
// baseline (2290.367 us; speedup 1.0000x reference)
//
#include <hip/hip_runtime.h>
#include <hip/hip_cooperative_groups.h>
namespace cg = cooperative_groups;

typedef unsigned short u16;
using short8 = __attribute__((ext_vector_type(8))) short;
using f32x4  = __attribute__((ext_vector_type(4))) float;

#define NLAYER 4
#define DMODEL 1024
#define DSTATE 16
#define DINNER 2048
#define DTRANK 64
#define SEQL   1024
#define NBATCH 2
#define MTOK   2048   /* NBATCH*SEQL */
#define NCH    64     /* scan chunks per sequence */
#define CLEN   16     /* timesteps per chunk: NCH*CLEN == SEQL */
#define XPK    16     /* xproj splitK */

__device__ __forceinline__ u16 f2bf(float f) {
  union { float f; unsigned int u; } cv; cv.f = f;
  return (u16)((cv.u + 0x7FFFu + ((cv.u >> 16) & 1u)) >> 16);
}
__device__ __forceinline__ float bf2f(u16 v) {
  union { unsigned int u; float f; } cv; cv.u = ((unsigned int)v) << 16; return cv.f;
}

// ---------------- batched weight conversion (all layers in one launch) ----------------
__global__ __launch_bounds__(256) void f32_to_bf16_l(const float* __restrict__ src,
                                                     u16* __restrict__ dst, int nper) {
  int l = blockIdx.y;
  int i4 = (blockIdx.x * 256 + threadIdx.x) * 4;
  if (i4 >= nper) return;
  float4 v = *(const float4*)&src[(size_t)l * nper + i4];
  ushort4 o; o.x = f2bf(v.x); o.y = f2bf(v.y); o.z = f2bf(v.z); o.w = f2bf(v.w);
  *(ushort4*)&dst[(size_t)l * nper + i4] = o;
}

// x_proj_w (L x 96 x 2048) -> padded (L x 128 x 2048) bf16
__global__ __launch_bounds__(256) void cvt_pad_xproj_l(const float* __restrict__ src,
                                                       u16* __restrict__ dst) {
  int l = blockIdx.y;
  int i4 = (blockIdx.x * 256 + threadIdx.x) * 4;   // 128*2048 per layer
  int row = i4 >> 11, col = i4 & 2047;
  float4 v = make_float4(0.f, 0.f, 0.f, 0.f);
  if (row < 96) v = *(const float4*)&src[(size_t)l * 96 * 2048 + row * 2048 + col];
  ushort4 o; o.x = f2bf(v.x); o.y = f2bf(v.y); o.z = f2bf(v.z); o.w = f2bf(v.w);
  *(ushort4*)&dst[(size_t)l * 128 * 2048 + i4] = o;
}

// ---------------- LayerNorm -> bf16 (row = 1024) ----------------
__global__ __launch_bounds__(256) void ln_to_bf16_k(const float* __restrict__ X,
    const float* __restrict__ w, const float* __restrict__ b, u16* __restrict__ out) {
  int row = blockIdx.x, tid = threadIdx.x;
  const float* x = X + (size_t)row * 1024;
  float4 v = ((const float4*)x)[tid];
  float s = v.x + v.y + v.z + v.w;
  float q = v.x*v.x + v.y*v.y + v.z*v.z + v.w*v.w;
  for (int o = 32; o; o >>= 1) { s += __shfl_down(s, o); q += __shfl_down(q, o); }
  __shared__ float sb[4], qb[4];
  int wv = tid >> 6, lane = tid & 63;
  if (lane == 0) { sb[wv] = s; qb[wv] = q; }
  __syncthreads();
  s = sb[0] + sb[1] + sb[2] + sb[3];
  q = qb[0] + qb[1] + qb[2] + qb[3];
  float mean = s * (1.f / 1024.f);
  float var  = q * (1.f / 1024.f) - mean * mean;
  float rstd = rsqrtf(var + 1e-5f);
  float4 wv4 = ((const float4*)w)[tid];
  float4 bv4 = ((const float4*)b)[tid];
  ushort4 o4;
  o4.x = f2bf((v.x - mean) * rstd * wv4.x + bv4.x);
  o4.y = f2bf((v.y - mean) * rstd * wv4.y + bv4.y);
  o4.z = f2bf((v.z - mean) * rstd * wv4.z + bv4.z);
  o4.w = f2bf((v.w - mean) * rstd * wv4.w + bv4.w);
  ((ushort4*)(out + (size_t)row * 1024))[tid] = o4;
}

// ---------------- staging helpers ----------------
// 256-thread version (gemm_dt_k): 2 x 16B per thread
__device__ __forceinline__ void stage_tile(const u16* G, int ld, int row0, int k0,
                                           u16* S, int tid) {
  int w = tid >> 6;
#pragma unroll
  for (int j = 0; j < 2; ++j) {
    int t = tid + j * 256;
    int r = t >> 2;
    int c = (t & 3) << 3;
    const u16* g = G + (size_t)(row0 + r) * ld + (k0 + c);
    u16* s = S + w * 512 + j * 2048;
    __builtin_amdgcn_global_load_lds((const __attribute__((address_space(1))) void*)g,
                                     (__attribute__((address_space(3))) void*)s,
                                     16, 0, 0);
  }
}
// 512-thread version: exactly one 16B per thread; LDS layout linear in tid
__device__ __forceinline__ void stage512(const u16* G, int ld, int row0, int k0,
                                         u16* S, int tid) {
  int r = tid >> 2;
  int c = (tid & 3) << 3;
  const u16* g = G + (size_t)(row0 + r) * ld + (k0 + c);
  u16* s = S + (tid >> 6) * 512;   // wave-uniform base; HW adds lane*16B
  __builtin_amdgcn_global_load_lds((const __attribute__((address_space(1))) void*)g,
                                   (__attribute__((address_space(3))) void*)s,
                                   16, 0, 0);
}

// ---------------- MFMA GEMM: C[M,N] = A[M,K] * W[N,K]^T ----------------
// 128x128 tile, 8 waves (each 64x32 = 4x2 frags), BK=32, double-buffered.
// EPI: 0 = f32 store to partial slice, 1 = bf16 store (coalesced via LDS), 3 = atomicAdd f32
// SWZ: 1 = XCD-chunked 1D grid
template<int EPI, int SWZ>
__global__ __launch_bounds__(512) void gemm_bt(const u16* __restrict__ A,
    const u16* __restrict__ Bw, float* __restrict__ C,
    int lda, int ldb, int ldc, int kchunk, int nbm, int zstride) {
  __shared__ u16 SMEM[16384];   // 32KB: 2x(As 8KB) + 2x(Bs 8KB); reused as C-tile for EPI=1
  u16* As0 = SMEM;
  u16* As1 = SMEM + 4096;
  u16* Bs0 = SMEM + 8192;
  u16* Bs1 = SMEM + 12288;
  int tid = threadIdx.x;
  int bm, bn;
  if (SWZ) {
    int l = blockIdx.x;
    int xcd = l & 7;
    int idx = l >> 3;
    int bnr = (int)(gridDim.x >> 3) / nbm;
    bm = idx % nbm;
    bn = xcd * bnr + idx / nbm;
  } else {
    bm = blockIdx.x; bn = blockIdx.y;
  }
  int kb = blockIdx.z * kchunk, ke = kb + kchunk;
  int lane = tid & 63;
  int w = tid >> 6;                 // 0..7
  int wr = (w >> 2) * 64;           // 0 or 64
  int wc = (w & 3) * 32;            // 0,32,64,96
  int fr = lane & 15;
  int kg = (lane >> 4) * 8;
  f32x4 acc[4][2] = {};
  int cur = 0;
  stage512(A, lda, bm * 128, kb, As0, tid);
  stage512(Bw, ldb, bn * 128, kb, Bs0, tid);
  __syncthreads();
  for (int k0 = kb; k0 < ke; k0 += 32) {
    int kn = k0 + 32;
    if (kn < ke) {
      stage512(A, lda, bm * 128, kn, cur ? As0 : As1, tid);
      stage512(Bw, ldb, bn * 128, kn, cur ? Bs0 : Bs1, tid);
    }
    const u16* Ac = cur ? As1 : As0;
    const u16* Bc = cur ? Bs1 : Bs0;
    short8 a[4], b[2];
#pragma unroll
    for (int mf = 0; mf < 4; ++mf)
      a[mf] = *(const short8*)&Ac[(wr + mf * 16 + fr) * 32 + kg];
#pragma unroll
    for (int nf = 0; nf < 2; ++nf)
      b[nf] = *(const short8*)&Bc[(wc + nf * 16 + fr) * 32 + kg];
#pragma unroll
    for (int mf = 0; mf < 4; ++mf)
#pragma unroll
      for (int nf = 0; nf < 2; ++nf)
        acc[mf][nf] = __builtin_amdgcn_mfma_f32_16x16x32_bf16(a[mf], b[nf], acc[mf][nf], 0, 0, 0);
    __syncthreads();
    cur ^= 1;
  }
  if (EPI == 1) {
    // stage bf16 C-tile in LDS, then fully-coalesced 16B stores
#pragma unroll
    for (int mf = 0; mf < 4; ++mf)
#pragma unroll
      for (int nf = 0; nf < 2; ++nf)
#pragma unroll
        for (int r = 0; r < 4; ++r) {
          int lr = wr + (lane >> 4) * 4 + mf * 16 + r;
          int lc = wc + fr + nf * 16;
          SMEM[lr * 128 + lc] = f2bf(acc[mf][nf][r]);
        }
    __syncthreads();
    int row = tid >> 2, c0l = (tid & 3) * 32;
    u16* dst = (u16*)C + (size_t)(bm * 128 + row) * ldc + bn * 128 + c0l;
    const u16* srcl = &SMEM[row * 128 + c0l];
#pragma unroll
    for (int s = 0; s < 4; ++s)
      *(short8*)&dst[s * 8] = *(const short8*)&srcl[s * 8];
  } else {
    int r0 = bm * 128 + wr + (lane >> 4) * 4;
    int c0 = bn * 128 + wc + fr;
    size_t zoff = (EPI == 0) ? (size_t)blockIdx.z * zstride : 0;
#pragma unroll
    for (int mf = 0; mf < 4; ++mf) {
#pragma unroll
      for (int nf = 0; nf < 2; ++nf) {
#pragma unroll
        for (int r = 0; r < 4; ++r) {
          int gr = r0 + mf * 16 + r;
          int gc = c0 + nf * 16;
          float v = acc[mf][nf][r];
          size_t idx = (size_t)gr * ldc + gc;
          if (EPI == 0) {
            C[zoff + idx] = v;
          } else {
            atomicAdd(&C[idx], v);
          }
        }
      }
    }
  }
}

// reduce xproj partials: xdbl_l[i] = sum_z part[z][i]
__global__ __launch_bounds__(256) void reduce_xdbl_k(const float* __restrict__ part,
                                                     float* __restrict__ xdbl_l) {
  int i4 = (blockIdx.x * 256 + threadIdx.x) * 4;   // 2048*128 total
  float4 s = *(const float4*)&part[i4];
#pragma unroll
  for (int z = 1; z < XPK; ++z) {
    float4 v = *(const float4*)&part[(size_t)z * (MTOK * 128) + i4];
    s.x += v.x; s.y += v.y; s.z += v.z; s.w += v.w;
  }
  *(float4*)&xdbl_l[i4] = s;
}

// ---------------- causal depthwise conv (K=4) + SiLU, bf16 in/out, 8 ch/thread ----------------
__global__ __launch_bounds__(256) void conv_silu_k(const u16* __restrict__ xzb,
    const float* __restrict__ cw, const float* __restrict__ cb,
    u16* __restrict__ xsb) {
  int idx = blockIdx.x * 256 + threadIdx.x;  // 2048 * 256
  int m = idx >> 8;
  int d = (idx & 255) << 3;
  int t = m & (SEQL - 1);
  float4 w4[8];
#pragma unroll
  for (int i = 0; i < 8; ++i) w4[i] = *(const float4*)&cw[(d + i) * 4];
  float acc[8];
#pragma unroll
  for (int q = 0; q < 2; ++q) {
    float4 c4 = *(const float4*)&cb[d + q * 4];
    acc[q*4+0] = c4.x; acc[q*4+1] = c4.y; acc[q*4+2] = c4.z; acc[q*4+3] = c4.w;
  }
#pragma unroll
  for (int j = 0; j < 4; ++j) {
    int tt = t - 3 + j;
    if (tt >= 0) {
      short8 xv = *(const short8*)&xzb[(size_t)(m - 3 + j) * 4096 + d];
#pragma unroll
      for (int i = 0; i < 8; ++i)
        acc[i] += bf2f((u16)xv[i]) * ((const float*)&w4[i])[j];
    }
  }
  short8 ob;
#pragma unroll
  for (int i = 0; i < 8; ++i) {
    float o = acc[i] / (1.f + __expf(-acc[i]));
    ob[i] = (short)f2bf(o);
  }
  *(short8*)&xsb[(size_t)m * 2048 + d] = ob;
}

// ---------------- dt GEMM: dt = softplus(xdbl[:, :64] @ w_dt^T + bias) -> bf16 ----------------
__global__ __launch_bounds__(256) void gemm_dt_k(const float* __restrict__ Af,
    const u16* __restrict__ Bw, const float* __restrict__ bias, u16* __restrict__ Cout) {
  __shared__ u16 As[128 * 32];
  __shared__ u16 Bs[128 * 32];
  int tid = threadIdx.x;
  int bm = blockIdx.x, bn = blockIdx.y;
  int lane = tid & 63, w = tid >> 6;
  int wr = (w >> 1) * 64, wc = (w & 1) * 64;
  int fr = lane & 15;
  int kg = (lane >> 4) * 8;
  f32x4 acc[4][4] = {};
  int r  = tid >> 1;
  int cc = (tid & 1) * 16;
  for (int k0 = 0; k0 < 64; k0 += 32) {
    const float* src = &Af[(size_t)(bm * 128 + r) * 128 + k0 + cc];
    float4 f0 = *(const float4*)&src[0];
    float4 f1 = *(const float4*)&src[4];
    float4 f2 = *(const float4*)&src[8];
    float4 f3 = *(const float4*)&src[12];
    short8 o0, o1;
    o0[0]=(short)f2bf(f0.x); o0[1]=(short)f2bf(f0.y); o0[2]=(short)f2bf(f0.z); o0[3]=(short)f2bf(f0.w);
    o0[4]=(short)f2bf(f1.x); o0[5]=(short)f2bf(f1.y); o0[6]=(short)f2bf(f1.z); o0[7]=(short)f2bf(f1.w);
    o1[0]=(short)f2bf(f2.x); o1[1]=(short)f2bf(f2.y); o1[2]=(short)f2bf(f2.z); o1[3]=(short)f2bf(f2.w);
    o1[4]=(short)f2bf(f3.x); o1[5]=(short)f2bf(f3.y); o1[6]=(short)f2bf(f3.z); o1[7]=(short)f2bf(f3.w);
    __syncthreads();
    *(short8*)&As[r * 32 + cc]     = o0;
    *(short8*)&As[r * 32 + cc + 8] = o1;
    stage_tile(Bw, 64, bn * 128, k0, Bs, tid);
    __syncthreads();
    short8 a[4], b[4];
#pragma unroll
    for (int mf = 0; mf < 4; ++mf)
      a[mf] = *(const short8*)&As[(wr + mf * 16 + fr) * 32 + kg];
#pragma unroll
    for (int nf = 0; nf < 4; ++nf)
      b[nf] = *(const short8*)&Bs[(wc + nf * 16 + fr) * 32 + kg];
#pragma unroll
    for (int mf = 0; mf < 4; ++mf)
#pragma unroll
      for (int nf = 0; nf < 4; ++nf)
        acc[mf][nf] = __builtin_amdgcn_mfma_f32_16x16x32_bf16(a[mf], b[nf], acc[mf][nf], 0, 0, 0);
  }
  int r0 = bm * 128 + wr + (lane >> 4) * 4;
  int c0 = bn * 128 + wc + fr;
#pragma unroll
  for (int mf = 0; mf < 4; ++mf)
#pragma unroll
    for (int nf = 0; nf < 4; ++nf)
#pragma unroll
      for (int rr = 0; rr < 4; ++rr) {
        int gr = r0 + mf * 16 + rr;
        int gc = c0 + nf * 16;
        float v = acc[mf][nf][rr] + bias[gc];
        v = (v > 20.f) ? v : log1pf(__expf(v));
        Cout[(size_t)gr * 2048 + gc] = f2bf(v);
      }
}

// ---------------- fused cooperative selective scan ----------------
// phase1: per (b,ch,d) local suffix S[16] + sumdt -> PS_S, sumdt_a
// phase2: parallel prefix (4 threads per (b,n,d), 16 chunks each) -> Hb (bf16)
// phase3: replay chunk with retained dt/x regs, emit gated y
__global__ __launch_bounds__(256) void scan_fused_k(const u16* __restrict__ dtb,
    const u16* __restrict__ xsb, const float* __restrict__ xdbl,
    const float* __restrict__ Alog, const float* __restrict__ Dv,
    const u16* __restrict__ xzb, float* __restrict__ PS_S,
    float* __restrict__ sumdt_a, u16* __restrict__ Hb, u16* __restrict__ yg) {
  cg::grid_group grid = cg::this_grid();
  __shared__ float smem[512];
  int tid = threadIdx.x;
  int dg = blockIdx.x & 7;
  int ch = (blockIdx.x >> 3) & (NCH - 1);
  int b  = blockIdx.x >> 9;
  int d  = dg * 256 + tid;
  float Ar[16];
#pragma unroll
  for (int q = 0; q < 4; ++q) {
    float4 a = *(const float4*)&Alog[d * 16 + q * 4];
    Ar[q*4+0] = -__expf(a.x); Ar[q*4+1] = -__expf(a.y);
    Ar[q*4+2] = -__expf(a.z); Ar[q*4+3] = -__expf(a.w);
  }
  // ---- phase 1 ----
  {
    int t = tid >> 4, n = tid & 15;
    int mm = b * SEQL + ch * CLEN + t;
    smem[t * 16 + n] = xdbl[mm * 128 + 64 + n];
  }
  __syncthreads();
  int mbase = b * SEQL + ch * CLEN;
  float dtv[CLEN], xv[CLEN];
#pragma unroll
  for (int t = 0; t < CLEN; ++t) dtv[t] = bf2f(dtb[(size_t)(mbase + t) * 2048 + d]);
#pragma unroll
  for (int t = 0; t < CLEN; ++t) xv[t] = bf2f(xsb[(size_t)(mbase + t) * 2048 + d]);
  {
    float S[16];
#pragma unroll
    for (int n = 0; n < 16; ++n) S[n] = 0.f;
    float sumdt = 0.f;
    for (int t = 0; t < CLEN; ++t) {
      sumdt += dtv[t];
      float dx = dtv[t] * xv[t];
#pragma unroll
      for (int n = 0; n < 16; ++n)
        S[n] = __expf(dtv[t] * Ar[n]) * S[n] + dx * smem[t * 16 + n];
    }
    size_t base = ((size_t)(b * NCH + ch) * 16) * 2048 + d;
#pragma unroll
    for (int n = 0; n < 16; ++n) PS_S[base + (size_t)n * 2048] = S[n];
    sumdt_a[(size_t)(b * NCH + ch) * 2048 + d] = sumdt;
  }
  __threadfence();
  grid.sync();
  // ---- phase 2: prefix ----
  {
    int id = blockIdx.x * 256 + tid;
    int q = id & 3;
    int item = id >> 2;
    int dd = item & 2047;
    int n2 = (item >> 11) & 15;
    int bb = item >> 15;
    float Arn = -__expf(Alog[dd * 16 + n2]);
    size_t sb = ((size_t)(bb * NCH) * 16 + n2) * 2048 + dd;
    size_t db = (size_t)(bb * NCH) * 2048 + dd;
    float Pl = 1.f, Sl = 0.f;
#pragma unroll
    for (int j = 0; j < 16; ++j) {
      int c2 = q * 16 + j;
      float Sv = PS_S[sb + (size_t)c2 * 32768];
      float Pv = __expf(Arn * sumdt_a[db + (size_t)c2 * 2048]);
      Sl = Pv * Sl + Sv;
      Pl = Pv * Pl;
    }
    smem[tid] = Pl; smem[256 + tid] = Sl;
    __syncthreads();
    int g = tid & ~3;
    float h = 0.f;
    for (int j = 0; j < q; ++j) h = smem[g + j] * h + smem[256 + g + j];
#pragma unroll
    for (int j = 0; j < 16; ++j) {
      int c2 = q * 16 + j;
      Hb[sb + (size_t)c2 * 32768] = f2bf(h);
      float Sv = PS_S[sb + (size_t)c2 * 32768];
      float Pv = __expf(Arn * sumdt_a[db + (size_t)c2 * 2048]);
      h = Pv * h + Sv;
    }
  }
  __threadfence();
  grid.sync();
  __syncthreads();
  // ---- phase 3 ----
  {
    int t = tid >> 5, n = tid & 31;
    int mm = b * SEQL + ch * CLEN + t;
    smem[t * 32 + n] = xdbl[mm * 128 + 64 + n];
    smem[(t + 8) * 32 + n] = xdbl[(mm + 8) * 128 + 64 + n];
  }
  float Dvd = Dv[d];
  size_t hbase = ((size_t)(b * NCH + ch) * 16) * 2048 + d;
  float h[16];
#pragma unroll
  for (int n = 0; n < 16; ++n) h[n] = bf2f(Hb[hbase + (size_t)n * 2048]);
  float zv[CLEN];
#pragma unroll
  for (int t = 0; t < CLEN; ++t) zv[t] = bf2f(xzb[(size_t)(mbase + t) * 4096 + 2048 + d]);
  __syncthreads();
  for (int t = 0; t < CLEN; ++t) {
    float dx = dtv[t] * xv[t];
#pragma unroll
    for (int n = 0; n < 16; ++n)
      h[n] = __expf(dtv[t] * Ar[n]) * h[n] + dx * smem[t * 32 + n];
    float y0 = 0.f, y1 = 0.f, y2 = 0.f, y3 = 0.f;
#pragma unroll
    for (int n = 0; n < 4; ++n) {
      y0 += h[n]      * smem[t * 32 + 16 + n];
      y1 += h[4 + n]  * smem[t * 32 + 20 + n];
      y2 += h[8 + n]  * smem[t * 32 + 24 + n];
      y3 += h[12 + n] * smem[t * 32 + 28 + n];
    }
    float y = (y0 + y1) + (y2 + y3) + xv[t] * Dvd;
    float sz = zv[t] / (1.f + __expf(-zv[t]));
    yg[(size_t)(mbase + t) * 2048 + d] = f2bf(y * sz);
  }
}

// ---------------- fused head ----------------
__global__ __launch_bounds__(256) void lnlast_gemv1_k(const float* __restrict__ xb,
    const float* __restrict__ fnw, const float* __restrict__ fnb,
    const float* __restrict__ h1w, const float* __restrict__ h1b,
    float* __restrict__ hpre) {
  int blk = blockIdx.x, tid = threadIdx.x;
  int b = blk >> 9;
  int jbase = (blk & 511) * 4;
  int wv = tid >> 6, lane = tid & 63;
  const float* x = xb + (size_t)(b * 1024 + 1023) * 1024;
  float4 v = ((const float4*)x)[tid];
  float s = v.x + v.y + v.z + v.w;
  float q = v.x*v.x + v.y*v.y + v.z*v.z + v.w*v.w;
  for (int o = 32; o; o >>= 1) { s += __shfl_down(s, o); q += __shfl_down(q, o); }
  __shared__ float sb[4], qb[4];
  __shared__ float row[1024];
  if (lane == 0) { sb[wv] = s; qb[wv] = q; }
  __syncthreads();
  s = sb[0] + sb[1] + sb[2] + sb[3];
  q = qb[0] + qb[1] + qb[2] + qb[3];
  float mean = s * (1.f / 1024.f);
  float rstd = rsqrtf(q * (1.f / 1024.f) - mean * mean + 1e-5f);
  float4 wv4 = ((const float4*)fnw)[tid];
  float4 bv4 = ((const float4*)fnb)[tid];
  float4 o;
  o.x = (v.x - mean) * rstd * wv4.x + bv4.x;
  o.y = (v.y - mean) * rstd * wv4.y + bv4.y;
  o.z = (v.z - mean) * rstd * wv4.z + bv4.z;
  o.w = (v.w - mean) * rstd * wv4.w + bv4.w;
  ((float4*)row)[tid] = o;
  __syncthreads();
  int j = jbase + wv;
  const float* w = h1w + (size_t)j * 1024;
  float acc = 0.f;
#pragma unroll
  for (int qq = 0; qq < 4; ++qq) {
    int col = qq * 256 + lane * 4;
    float4 xv = *(const float4*)&row[col];
    float4 wvv = *(const float4*)&w[col];
    acc += xv.x*wvv.x + xv.y*wvv.y + xv.z*wvv.z + xv.w*wvv.w;
  }
  for (int o2 = 32; o2; o2 >>= 1) acc += __shfl_down(acc, o2);
  if (lane == 0) hpre[b * 2048 + j] = acc + h1b[j];
}

__global__ __launch_bounds__(256) void lngelu_gemv2_k(const float* __restrict__ hpre,
    const float* __restrict__ hlnw, const float* __restrict__ hlnb,
    const float* __restrict__ h2w, const float* __restrict__ h2b,
    float* __restrict__ out) {
  int blk = blockIdx.x, tid = threadIdx.x;
  int b = (blk >= 250) ? 1 : 0;
  int jbase = (blk - b * 250) * 4;
  int wv = tid >> 6, lane = tid & 63;
  const float* x = hpre + b * 2048;
  float4 v0 = ((const float4*)x)[tid];
  float4 v1 = ((const float4*)x)[tid + 256];
  float s = v0.x+v0.y+v0.z+v0.w + v1.x+v1.y+v1.z+v1.w;
  float q = v0.x*v0.x+v0.y*v0.y+v0.z*v0.z+v0.w*v0.w
          + v1.x*v1.x+v1.y*v1.y+v1.z*v1.z+v1.w*v1.w;
  for (int o = 32; o; o >>= 1) { s += __shfl_down(s, o); q += __shfl_down(q, o); }
  __shared__ float sb[4], qb[4];
  __shared__ float row[2048];
  if (lane == 0) { sb[wv] = s; qb[wv] = q; }
  __syncthreads();
  s = sb[0] + sb[1] + sb[2] + sb[3];
  q = qb[0] + qb[1] + qb[2] + qb[3];
  float mean = s * (1.f / 2048.f);
  float rstd = rsqrtf(q * (1.f / 2048.f) - mean * mean + 1e-5f);
#pragma unroll
  for (int h = 0; h < 2; ++h) {
    float4 v = h ? v1 : v0;
    int c0 = tid * 4 + h * 1024;
    float4 wv4 = *(const float4*)&hlnw[c0];
    float4 bv4 = *(const float4*)&hlnb[c0];
    float4 g;
    g.x = (v.x - mean) * rstd * wv4.x + bv4.x;
    g.y = (v.y - mean) * rstd * wv4.y + bv4.y;
    g.z = (v.z - mean) * rstd * wv4.z + bv4.z;
    g.w = (v.w - mean) * rstd * wv4.w + bv4.w;
    g.x = 0.5f * g.x * (1.f + erff(g.x * 0.70710678f));
    g.y = 0.5f * g.y * (1.f + erff(g.y * 0.70710678f));
    g.z = 0.5f * g.z * (1.f + erff(g.z * 0.70710678f));
    g.w = 0.5f * g.w * (1.f + erff(g.w * 0.70710678f));
    *(float4*)&row[c0] = g;
  }
  __syncthreads();
  int j = jbase + wv;
  const float* w = h2w + (size_t)j * 2048;
  float acc = 0.f;
#pragma unroll
  for (int qq = 0; qq < 8; ++qq) {
    int col = qq * 256 + lane * 4;
    float4 xv = *(const float4*)&row[col];
    float4 wvv = *(const float4*)&w[col];
    acc += xv.x*wvv.x + xv.y*wvv.y + xv.z*wvv.z + xv.w*wvv.w;
  }
  for (int o2 = 32; o2; o2 >>= 1) acc += __shfl_down(acc, o2);
  if (lane == 0) out[b * 1000 + j] = acc + h2b[j];
}

// ---------------- launch ----------------
extern "C" void kernel_launch(void* const* d_in, const int* in_sizes, int n_in,
                              void* d_out, int out_size, void* d_ws, size_t ws_size,
                              hipStream_t stream) {
  const float* x_in = (const float*)d_in[0];
  const float* lnw  = (const float*)d_in[1];
  const float* lnb  = (const float*)d_in[2];
  const float* ipw  = (const float*)d_in[3];
  const float* cw   = (const float*)d_in[4];
  const float* cb   = (const float*)d_in[5];
  const float* xpw  = (const float*)d_in[6];
  const float* dpw  = (const float*)d_in[7];
  const float* dpb  = (const float*)d_in[8];
  const float* Alog = (const float*)d_in[9];
  const float* Dv   = (const float*)d_in[10];
  const float* opw  = (const float*)d_in[11];
  const float* fnw  = (const float*)d_in[12];
  const float* fnb  = (const float*)d_in[13];
  const float* h1w  = (const float*)d_in[14];
  const float* h1b  = (const float*)d_in[15];
  const float* hlnw = (const float*)d_in[16];
  const float* hlnb = (const float*)d_in[17];
  const float* h2w  = (const float*)d_in[18];
  const float* h2b  = (const float*)d_in[19];
  float* out = (float*)d_out;

  char* ws = (char*)d_ws;
  size_t off = 0;
  auto alloc = [&](size_t bytes) -> void* {
    void* p = ws + off; off += (bytes + 255) & ~(size_t)255; return p;
  };
  float* x_buf   = (float*)alloc((size_t)MTOK * DMODEL * 4);
  u16*   xn_bf   = (u16*)  alloc((size_t)MTOK * DMODEL * 2);
  u16*   xz_bf   = (u16*)  alloc((size_t)MTOK * 2 * DINNER * 2);
  u16*   xs_bf   = (u16*)  alloc((size_t)MTOK * DINNER * 2);
  float* xpart   = (float*)alloc((size_t)XPK * MTOK * 128 * 4);
  float* xdbl_l  = (float*)alloc((size_t)MTOK * 128 * 4);
  u16*   dtb     = (u16*)  alloc((size_t)MTOK * DINNER * 2);
  u16*   yg_bf   = (u16*)  alloc((size_t)MTOK * DINNER * 2);
  u16*   w_ip4   = (u16*)  alloc((size_t)NLAYER * 2 * DINNER * DMODEL * 2);
  u16*   w_xp4   = (u16*)  alloc((size_t)NLAYER * 128 * DINNER * 2);
  u16*   w_dt4   = (u16*)  alloc((size_t)NLAYER * DINNER * DTRANK * 2);
  u16*   w_op4   = (u16*)  alloc((size_t)NLAYER * DMODEL * DINNER * 2);
  float* PS_S    = (float*)alloc((size_t)NBATCH * NCH * 16 * 2048 * 4);
  float* sumdt_a = (float*)alloc((size_t)NBATCH * NCH * 2048 * 4);
  u16*   Hb      = (u16*)  alloc((size_t)NBATCH * NCH * 16 * 2048 * 2);
  float* hpre    = (float*)alloc(2 * 2048 * 4);

  hipMemcpyAsync(x_buf, x_in, (size_t)MTOK * DMODEL * 4, hipMemcpyDeviceToDevice, stream);
  { dim3 g(4096, 4); f32_to_bf16_l<<<g, 256, 0, stream>>>(ipw, w_ip4, 2 * DINNER * DMODEL); }
  { dim3 g(256, 4);  cvt_pad_xproj_l<<<g, 256, 0, stream>>>(xpw, w_xp4); }
  { dim3 g(128, 4);  f32_to_bf16_l<<<g, 256, 0, stream>>>(dpw, w_dt4, DINNER * DTRANK); }
  { dim3 g(2048, 4); f32_to_bf16_l<<<g, 256, 0, stream>>>(opw, w_op4, DMODEL * DINNER); }

  for (int i = 0; i < NLAYER; ++i) {
    ln_to_bf16_k<<<MTOK, 256, 0, stream>>>(x_buf, lnw + i * DMODEL, lnb + i * DMODEL, xn_bf);
    gemm_bt<1, 1><<<dim3(512, 1, 1), 512, 0, stream>>>(
        xn_bf, w_ip4 + (size_t)i * 2 * DINNER * DMODEL, (float*)xz_bf,
        1024, 1024, 4096, 1024, 16, 0);
    conv_silu_k<<<2048, 256, 0, stream>>>(xz_bf, cw + (size_t)i * DINNER * 4, cb + i * DINNER, xs_bf);
    { dim3 g(16, 1, XPK);
      gemm_bt<0, 0><<<g, 512, 0, stream>>>(xs_bf, w_xp4 + (size_t)i * 128 * DINNER,
                                           xpart, 2048, 2048, 128, 128, 16, MTOK * 128); }
    reduce_xdbl_k<<<256, 256, 0, stream>>>(xpart, xdbl_l);
    { dim3 g(16, 16, 1);
      gemm_dt_k<<<g, 256, 0, stream>>>(xdbl_l, w_dt4 + (size_t)i * DINNER * DTRANK,
                                       dpb + i * DINNER, dtb); }
    {
      const u16*   a0 = dtb;
      const u16*   a1 = xs_bf;
      const float* a2 = xdbl_l;
      const float* a3 = Alog + (size_t)i * DINNER * DSTATE;
      const float* a4 = Dv + (size_t)i * DINNER;
      const u16*   a5 = xz_bf;
      float*       a6 = PS_S;
      float*       a7 = sumdt_a;
      u16*         a8 = Hb;
      u16*         a9 = yg_bf;
      void* kargs[10] = {&a0, &a1, &a2, &a3, &a4, &a5, &a6, &a7, &a8, &a9};
      hipLaunchCooperativeKernel((const void*)scan_fused_k, dim3(1024), dim3(256),
                                 kargs, 0, stream);
    }
    gemm_bt<3, 1><<<dim3(128, 1, 2), 512, 0, stream>>>(
        yg_bf, w_op4 + (size_t)i * DMODEL * DINNER, x_buf,
        2048, 2048, 1024, 1024, 16, 0);
  }
  lnlast_gemv1_k<<<1024, 256, 0, stream>>>(x_buf, fnw, fnb, h1w, h1b, hpre);
  lngelu_gemv2_k<<<500, 256, 0, stream>>>(hpre, hlnw, hlnb, h2w, h2b, out);
  (void)in_sizes; (void)n_in; (void)out_size; (void)ws_size;
}

// Round 10
// 683.006 us; speedup vs baseline: 3.3534x; 3.3534x over previous
//
#include <hip/hip_runtime.h>

typedef unsigned short u16;
using short8 = __attribute__((ext_vector_type(8))) short;
using f32x4  = __attribute__((ext_vector_type(4))) float;

#define NLAYER 4
#define DMODEL 1024
#define DSTATE 16
#define DINNER 2048
#define DTRANK 64
#define SEQL   1024
#define NBATCH 2
#define MTOK   2048   /* NBATCH*SEQL */
#define NCH    64     /* scan chunks per sequence */
#define CLEN   16     /* timesteps per chunk: NCH*CLEN == SEQL */
#define XPK    16     /* xproj splitK */

__device__ __forceinline__ u16 f2bf(float f) {
  union { float f; unsigned int u; } cv; cv.f = f;
  return (u16)((cv.u + 0x7FFFu + ((cv.u >> 16) & 1u)) >> 16);
}
__device__ __forceinline__ float bf2f(u16 v) {
  union { unsigned int u; float f; } cv; cv.u = ((unsigned int)v) << 16; return cv.f;
}

// ---------------- batched weight conversion (all layers in one launch) ----------------
__global__ __launch_bounds__(256) void f32_to_bf16_l(const float* __restrict__ src,
                                                     u16* __restrict__ dst, int nper) {
  int l = blockIdx.y;
  int i4 = (blockIdx.x * 256 + threadIdx.x) * 4;
  if (i4 >= nper) return;
  float4 v = *(const float4*)&src[(size_t)l * nper + i4];
  ushort4 o; o.x = f2bf(v.x); o.y = f2bf(v.y); o.z = f2bf(v.z); o.w = f2bf(v.w);
  *(ushort4*)&dst[(size_t)l * nper + i4] = o;
}

// x_proj_w (L x 96 x 2048) -> padded (L x 128 x 2048) bf16
__global__ __launch_bounds__(256) void cvt_pad_xproj_l(const float* __restrict__ src,
                                                       u16* __restrict__ dst) {
  int l = blockIdx.y;
  int i4 = (blockIdx.x * 256 + threadIdx.x) * 4;   // 128*2048 per layer
  int row = i4 >> 11, col = i4 & 2047;
  float4 v = make_float4(0.f, 0.f, 0.f, 0.f);
  if (row < 96) v = *(const float4*)&src[(size_t)l * 96 * 2048 + row * 2048 + col];
  ushort4 o; o.x = f2bf(v.x); o.y = f2bf(v.y); o.z = f2bf(v.z); o.w = f2bf(v.w);
  *(ushort4*)&dst[(size_t)l * 128 * 2048 + i4] = o;
}

// ---------------- LayerNorm -> bf16 (row = 1024) ----------------
__global__ __launch_bounds__(256) void ln_to_bf16_k(const float* __restrict__ X,
    const float* __restrict__ w, const float* __restrict__ b, u16* __restrict__ out) {
  int row = blockIdx.x, tid = threadIdx.x;
  const float* x = X + (size_t)row * 1024;
  float4 v = ((const float4*)x)[tid];
  float s = v.x + v.y + v.z + v.w;
  float q = v.x*v.x + v.y*v.y + v.z*v.z + v.w*v.w;
  for (int o = 32; o; o >>= 1) { s += __shfl_down(s, o); q += __shfl_down(q, o); }
  __shared__ float sb[4], qb[4];
  int wv = tid >> 6, lane = tid & 63;
  if (lane == 0) { sb[wv] = s; qb[wv] = q; }
  __syncthreads();
  s = sb[0] + sb[1] + sb[2] + sb[3];
  q = qb[0] + qb[1] + qb[2] + qb[3];
  float mean = s * (1.f / 1024.f);
  float var  = q * (1.f / 1024.f) - mean * mean;
  float rstd = rsqrtf(var + 1e-5f);
  float4 wv4 = ((const float4*)w)[tid];
  float4 bv4 = ((const float4*)b)[tid];
  ushort4 o4;
  o4.x = f2bf((v.x - mean) * rstd * wv4.x + bv4.x);
  o4.y = f2bf((v.y - mean) * rstd * wv4.y + bv4.y);
  o4.z = f2bf((v.z - mean) * rstd * wv4.z + bv4.z);
  o4.w = f2bf((v.w - mean) * rstd * wv4.w + bv4.w);
  ((ushort4*)(out + (size_t)row * 1024))[tid] = o4;
}

// ---------------- staging helpers ----------------
__device__ __forceinline__ void stage_tile(const u16* G, int ld, int row0, int k0,
                                           u16* S, int tid) {
  int w = tid >> 6;
#pragma unroll
  for (int j = 0; j < 2; ++j) {
    int t = tid + j * 256;
    int r = t >> 2;
    int c = (t & 3) << 3;
    const u16* g = G + (size_t)(row0 + r) * ld + (k0 + c);
    u16* s = S + w * 512 + j * 2048;
    __builtin_amdgcn_global_load_lds((const __attribute__((address_space(1))) void*)g,
                                     (__attribute__((address_space(3))) void*)s,
                                     16, 0, 0);
  }
}
__device__ __forceinline__ void stage512(const u16* G, int ld, int row0, int k0,
                                         u16* S, int tid) {
  int r = tid >> 2;
  int c = (tid & 3) << 3;
  const u16* g = G + (size_t)(row0 + r) * ld + (k0 + c);
  u16* s = S + (tid >> 6) * 512;   // wave-uniform base; HW adds lane*16B
  __builtin_amdgcn_global_load_lds((const __attribute__((address_space(1))) void*)g,
                                   (__attribute__((address_space(3))) void*)s,
                                   16, 0, 0);
}

// ---------------- MFMA GEMM: C[M,N] = A[M,K] * W[N,K]^T ----------------
// 128x128 tile, 8 waves (each 64x32 = 4x2 frags), BK=32, double-buffered.
// EPI: 0 = f32 store to partial slice, 1 = bf16 store (coalesced via LDS), 3 = atomicAdd f32
// SWZ: 1 = XCD-chunked 1D grid
template<int EPI, int SWZ>
__global__ __launch_bounds__(512) void gemm_bt(const u16* __restrict__ A,
    const u16* __restrict__ Bw, float* __restrict__ C,
    int lda, int ldb, int ldc, int kchunk, int nbm, int zstride) {
  __shared__ u16 SMEM[16384];   // 32KB: 2x(As 8KB) + 2x(Bs 8KB); reused as C-tile for EPI=1
  u16* As0 = SMEM;
  u16* As1 = SMEM + 4096;
  u16* Bs0 = SMEM + 8192;
  u16* Bs1 = SMEM + 12288;
  int tid = threadIdx.x;
  int bm, bn;
  if (SWZ) {
    int l = blockIdx.x;
    int xcd = l & 7;
    int idx = l >> 3;
    int bnr = (int)(gridDim.x >> 3) / nbm;
    bm = idx % nbm;
    bn = xcd * bnr + idx / nbm;
  } else {
    bm = blockIdx.x; bn = blockIdx.y;
  }
  int kb = blockIdx.z * kchunk, ke = kb + kchunk;
  int lane = tid & 63;
  int w = tid >> 6;                 // 0..7
  int wr = (w >> 2) * 64;           // 0 or 64
  int wc = (w & 3) * 32;            // 0,32,64,96
  int fr = lane & 15;
  int kg = (lane >> 4) * 8;
  f32x4 acc[4][2] = {};
  int cur = 0;
  stage512(A, lda, bm * 128, kb, As0, tid);
  stage512(Bw, ldb, bn * 128, kb, Bs0, tid);
  __syncthreads();
  for (int k0 = kb; k0 < ke; k0 += 32) {
    int kn = k0 + 32;
    if (kn < ke) {
      stage512(A, lda, bm * 128, kn, cur ? As0 : As1, tid);
      stage512(Bw, ldb, bn * 128, kn, cur ? Bs0 : Bs1, tid);
    }
    const u16* Ac = cur ? As1 : As0;
    const u16* Bc = cur ? Bs1 : Bs0;
    short8 a[4], b[2];
#pragma unroll
    for (int mf = 0; mf < 4; ++mf)
      a[mf] = *(const short8*)&Ac[(wr + mf * 16 + fr) * 32 + kg];
#pragma unroll
    for (int nf = 0; nf < 2; ++nf)
      b[nf] = *(const short8*)&Bc[(wc + nf * 16 + fr) * 32 + kg];
#pragma unroll
    for (int mf = 0; mf < 4; ++mf)
#pragma unroll
      for (int nf = 0; nf < 2; ++nf)
        acc[mf][nf] = __builtin_amdgcn_mfma_f32_16x16x32_bf16(a[mf], b[nf], acc[mf][nf], 0, 0, 0);
    __syncthreads();
    cur ^= 1;
  }
  if (EPI == 1) {
    // stage bf16 C-tile in LDS, then fully-coalesced 16B stores
#pragma unroll
    for (int mf = 0; mf < 4; ++mf)
#pragma unroll
      for (int nf = 0; nf < 2; ++nf)
#pragma unroll
        for (int r = 0; r < 4; ++r) {
          int lr = wr + (lane >> 4) * 4 + mf * 16 + r;
          int lc = wc + fr + nf * 16;
          SMEM[lr * 128 + lc] = f2bf(acc[mf][nf][r]);
        }
    __syncthreads();
    int row = tid >> 2, c0l = (tid & 3) * 32;
    u16* dst = (u16*)C + (size_t)(bm * 128 + row) * ldc + bn * 128 + c0l;
    const u16* srcl = &SMEM[row * 128 + c0l];
#pragma unroll
    for (int s = 0; s < 4; ++s)
      *(short8*)&dst[s * 8] = *(const short8*)&srcl[s * 8];
  } else {
    int r0 = bm * 128 + wr + (lane >> 4) * 4;
    int c0 = bn * 128 + wc + fr;
    size_t zoff = (EPI == 0) ? (size_t)blockIdx.z * zstride : 0;
#pragma unroll
    for (int mf = 0; mf < 4; ++mf) {
#pragma unroll
      for (int nf = 0; nf < 2; ++nf) {
#pragma unroll
        for (int r = 0; r < 4; ++r) {
          int gr = r0 + mf * 16 + r;
          int gc = c0 + nf * 16;
          float v = acc[mf][nf][r];
          size_t idx = (size_t)gr * ldc + gc;
          if (EPI == 0) {
            C[zoff + idx] = v;
          } else {
            atomicAdd(&C[idx], v);
          }
        }
      }
    }
  }
}

// reduce xproj partials: xdbl_l[i] = sum_z part[z][i]
__global__ __launch_bounds__(256) void reduce_xdbl_k(const float* __restrict__ part,
                                                     float* __restrict__ xdbl_l) {
  int i4 = (blockIdx.x * 256 + threadIdx.x) * 4;   // 2048*128 total
  float4 s = *(const float4*)&part[i4];
#pragma unroll
  for (int z = 1; z < XPK; ++z) {
    float4 v = *(const float4*)&part[(size_t)z * (MTOK * 128) + i4];
    s.x += v.x; s.y += v.y; s.z += v.z; s.w += v.w;
  }
  *(float4*)&xdbl_l[i4] = s;
}

// ---------------- causal depthwise conv (K=4) + SiLU, bf16 in/out, 8 ch/thread ----------------
__global__ __launch_bounds__(256) void conv_silu_k(const u16* __restrict__ xzb,
    const float* __restrict__ cw, const float* __restrict__ cb,
    u16* __restrict__ xsb) {
  int idx = blockIdx.x * 256 + threadIdx.x;  // 2048 * 256
  int m = idx >> 8;
  int d = (idx & 255) << 3;
  int t = m & (SEQL - 1);
  float4 w4[8];
#pragma unroll
  for (int i = 0; i < 8; ++i) w4[i] = *(const float4*)&cw[(d + i) * 4];
  float acc[8];
#pragma unroll
  for (int q = 0; q < 2; ++q) {
    float4 c4 = *(const float4*)&cb[d + q * 4];
    acc[q*4+0] = c4.x; acc[q*4+1] = c4.y; acc[q*4+2] = c4.z; acc[q*4+3] = c4.w;
  }
#pragma unroll
  for (int j = 0; j < 4; ++j) {
    int tt = t - 3 + j;
    if (tt >= 0) {
      short8 xv = *(const short8*)&xzb[(size_t)(m - 3 + j) * 4096 + d];
#pragma unroll
      for (int i = 0; i < 8; ++i)
        acc[i] += bf2f((u16)xv[i]) * ((const float*)&w4[i])[j];
    }
  }
  short8 ob;
#pragma unroll
  for (int i = 0; i < 8; ++i) {
    float o = acc[i] / (1.f + __expf(-acc[i]));
    ob[i] = (short)f2bf(o);
  }
  *(short8*)&xsb[(size_t)m * 2048 + d] = ob;
}

// ---------------- dt GEMM: dt = softplus(xdbl[:, :64] @ w_dt^T + bias) -> bf16 ----------------
__global__ __launch_bounds__(256) void gemm_dt_k(const float* __restrict__ Af,
    const u16* __restrict__ Bw, const float* __restrict__ bias, u16* __restrict__ Cout) {
  __shared__ u16 As[128 * 32];
  __shared__ u16 Bs[128 * 32];
  int tid = threadIdx.x;
  int bm = blockIdx.x, bn = blockIdx.y;
  int lane = tid & 63, w = tid >> 6;
  int wr = (w >> 1) * 64, wc = (w & 1) * 64;
  int fr = lane & 15;
  int kg = (lane >> 4) * 8;
  f32x4 acc[4][4] = {};
  int r  = tid >> 1;
  int cc = (tid & 1) * 16;
  for (int k0 = 0; k0 < 64; k0 += 32) {
    const float* src = &Af[(size_t)(bm * 128 + r) * 128 + k0 + cc];
    float4 f0 = *(const float4*)&src[0];
    float4 f1 = *(const float4*)&src[4];
    float4 f2 = *(const float4*)&src[8];
    float4 f3 = *(const float4*)&src[12];
    short8 o0, o1;
    o0[0]=(short)f2bf(f0.x); o0[1]=(short)f2bf(f0.y); o0[2]=(short)f2bf(f0.z); o0[3]=(short)f2bf(f0.w);
    o0[4]=(short)f2bf(f1.x); o0[5]=(short)f2bf(f1.y); o0[6]=(short)f2bf(f1.z); o0[7]=(short)f2bf(f1.w);
    o1[0]=(short)f2bf(f2.x); o1[1]=(short)f2bf(f2.y); o1[2]=(short)f2bf(f2.z); o1[3]=(short)f2bf(f2.w);
    o1[4]=(short)f2bf(f3.x); o1[5]=(short)f2bf(f3.y); o1[6]=(short)f2bf(f3.z); o1[7]=(short)f2bf(f3.w);
    __syncthreads();
    *(short8*)&As[r * 32 + cc]     = o0;
    *(short8*)&As[r * 32 + cc + 8] = o1;
    stage_tile(Bw, 64, bn * 128, k0, Bs, tid);
    __syncthreads();
    short8 a[4], b[4];
#pragma unroll
    for (int mf = 0; mf < 4; ++mf)
      a[mf] = *(const short8*)&As[(wr + mf * 16 + fr) * 32 + kg];
#pragma unroll
    for (int nf = 0; nf < 4; ++nf)
      b[nf] = *(const short8*)&Bs[(wc + nf * 16 + fr) * 32 + kg];
#pragma unroll
    for (int mf = 0; mf < 4; ++mf)
#pragma unroll
      for (int nf = 0; nf < 4; ++nf)
        acc[mf][nf] = __builtin_amdgcn_mfma_f32_16x16x32_bf16(a[mf], b[nf], acc[mf][nf], 0, 0, 0);
  }
  int r0 = bm * 128 + wr + (lane >> 4) * 4;
  int c0 = bn * 128 + wc + fr;
#pragma unroll
  for (int mf = 0; mf < 4; ++mf)
#pragma unroll
    for (int nf = 0; nf < 4; ++nf)
#pragma unroll
      for (int rr = 0; rr < 4; ++rr) {
        int gr = r0 + mf * 16 + rr;
        int gc = c0 + nf * 16;
        float v = acc[mf][nf][rr] + bias[gc];
        v = (v > 20.f) ? v : log1pf(__expf(v));
        Cout[(size_t)gr * 2048 + gc] = f2bf(v);
      }
}

// ---------------- chunked selective scan (3 kernels, R8-proven) ----------------
__global__ __launch_bounds__(256) void scan_part1(const u16* __restrict__ dtb,
    const u16* __restrict__ xsb, const float* __restrict__ xdbl,
    const float* __restrict__ Alog, float* __restrict__ PS_S, float* __restrict__ sumdt_a) {
  int tid = threadIdx.x;
  int dg = blockIdx.x & 7;
  int ch = (blockIdx.x >> 3) & (NCH - 1);
  int b  = blockIdx.x >> 9;
  int d  = dg * 256 + tid;
  float Ar[16];
#pragma unroll
  for (int q = 0; q < 4; ++q) {
    float4 a = *(const float4*)&Alog[d * 16 + q * 4];
    Ar[q*4+0] = -__expf(a.x); Ar[q*4+1] = -__expf(a.y);
    Ar[q*4+2] = -__expf(a.z); Ar[q*4+3] = -__expf(a.w);
  }
  __shared__ float Bsh[CLEN][16];
  {
    int t = tid >> 4, n = tid & 15;
    int mm = b * SEQL + ch * CLEN + t;
    Bsh[t][n] = xdbl[mm * 128 + 64 + n];
  }
  __syncthreads();
  int mbase = b * SEQL + ch * CLEN;
  float dtv[CLEN], xv[CLEN];
#pragma unroll
  for (int t = 0; t < CLEN; ++t) dtv[t] = bf2f(dtb[(size_t)(mbase + t) * 2048 + d]);
#pragma unroll
  for (int t = 0; t < CLEN; ++t) xv[t] = bf2f(xsb[(size_t)(mbase + t) * 2048 + d]);
  float S[16];
#pragma unroll
  for (int n = 0; n < 16; ++n) S[n] = 0.f;
  float sumdt = 0.f;
  for (int t = 0; t < CLEN; ++t) {
    sumdt += dtv[t];
    float dx = dtv[t] * xv[t];
    float4 B0 = *(const float4*)&Bsh[t][0];
    float4 B1 = *(const float4*)&Bsh[t][4];
    float4 B2 = *(const float4*)&Bsh[t][8];
    float4 B3 = *(const float4*)&Bsh[t][12];
    const float* Bp[4] = {(const float*)&B0, (const float*)&B1, (const float*)&B2, (const float*)&B3};
#pragma unroll
    for (int n = 0; n < 16; ++n)
      S[n] = __expf(dtv[t] * Ar[n]) * S[n] + dx * Bp[n >> 2][n & 3];
  }
  size_t base = ((size_t)(b * NCH + ch) * 16) * 2048 + d;
#pragma unroll
  for (int n = 0; n < 16; ++n) PS_S[base + (size_t)n * 2048] = S[n];
  sumdt_a[(size_t)(b * NCH + ch) * 2048 + d] = sumdt;
}

__global__ __launch_bounds__(256) void scan_prefix(const float* __restrict__ PS_S,
    const float* __restrict__ sumdt_a, const float* __restrict__ Alog,
    u16* __restrict__ Hb) {
  int id = blockIdx.x * 256 + threadIdx.x;   // 2*16*2048 = 65536
  int d = id & 2047;
  int n = (id >> 11) & 15;
  int b = id >> 15;
  float Ar = -__expf(Alog[d * 16 + n]);
  size_t sbase = ((size_t)(b * NCH) * 16 + n) * 2048 + d;
  size_t dbase = (size_t)(b * NCH) * 2048 + d;
  float h = 0.f;
#pragma unroll 8
  for (int ch = 0; ch < NCH; ++ch) {
    Hb[sbase + (size_t)ch * (16 * 2048)] = f2bf(h);
    float S  = PS_S[sbase + (size_t)ch * (16 * 2048)];
    float sd = sumdt_a[dbase + (size_t)ch * 2048];
    h = fmaf(__expf(Ar * sd), h, S);
  }
}

__global__ __launch_bounds__(256) void scan_part2(const u16* __restrict__ dtb,
    const u16* __restrict__ xsb, const float* __restrict__ xdbl,
    const float* __restrict__ Alog, const float* __restrict__ Dv,
    const u16* __restrict__ xzb, const u16* __restrict__ Hb,
    u16* __restrict__ yg) {
  int tid = threadIdx.x;
  int dg = blockIdx.x & 7;
  int ch = (blockIdx.x >> 3) & (NCH - 1);
  int b  = blockIdx.x >> 9;
  int d  = dg * 256 + tid;
  float Ar[16];
#pragma unroll
  for (int q = 0; q < 4; ++q) {
    float4 a = *(const float4*)&Alog[d * 16 + q * 4];
    Ar[q*4+0] = -__expf(a.x); Ar[q*4+1] = -__expf(a.y);
    Ar[q*4+2] = -__expf(a.z); Ar[q*4+3] = -__expf(a.w);
  }
  float Dvd = Dv[d];
  __shared__ float BCs[CLEN][32];
  {
    int t = tid >> 5, n = tid & 31;
    int mm = b * SEQL + ch * CLEN + t;
    BCs[t][n] = xdbl[mm * 128 + 64 + n];
    BCs[t + 8][n] = xdbl[(mm + 8) * 128 + 64 + n];
  }
  size_t hbase = ((size_t)(b * NCH + ch) * 16) * 2048 + d;
  float h[16];
#pragma unroll
  for (int n = 0; n < 16; ++n) h[n] = bf2f(Hb[hbase + (size_t)n * 2048]);
  int mbase = b * SEQL + ch * CLEN;
  float dtv[CLEN], xv[CLEN], zv[CLEN];
#pragma unroll
  for (int t = 0; t < CLEN; ++t) dtv[t] = bf2f(dtb[(size_t)(mbase + t) * 2048 + d]);
#pragma unroll
  for (int t = 0; t < CLEN; ++t) xv[t] = bf2f(xsb[(size_t)(mbase + t) * 2048 + d]);
#pragma unroll
  for (int t = 0; t < CLEN; ++t) zv[t] = bf2f(xzb[(size_t)(mbase + t) * 4096 + 2048 + d]);
  __syncthreads();
  for (int t = 0; t < CLEN; ++t) {
    float dx = dtv[t] * xv[t];
    float4 B0 = *(const float4*)&BCs[t][0];
    float4 B1 = *(const float4*)&BCs[t][4];
    float4 B2 = *(const float4*)&BCs[t][8];
    float4 B3 = *(const float4*)&BCs[t][12];
    float4 C0 = *(const float4*)&BCs[t][16];
    float4 C1 = *(const float4*)&BCs[t][20];
    float4 C2 = *(const float4*)&BCs[t][24];
    float4 C3 = *(const float4*)&BCs[t][28];
    const float* Bp[4] = {(const float*)&B0, (const float*)&B1, (const float*)&B2, (const float*)&B3};
    const float* Cp[4] = {(const float*)&C0, (const float*)&C1, (const float*)&C2, (const float*)&C3};
#pragma unroll
    for (int n = 0; n < 16; ++n)
      h[n] = __expf(dtv[t] * Ar[n]) * h[n] + dx * Bp[n >> 2][n & 3];
    float y0 = 0.f, y1 = 0.f, y2 = 0.f, y3 = 0.f;
#pragma unroll
    for (int n = 0; n < 4; ++n) {
      y0 += h[n]      * Cp[0][n];
      y1 += h[4 + n]  * Cp[1][n];
      y2 += h[8 + n]  * Cp[2][n];
      y3 += h[12 + n] * Cp[3][n];
    }
    float y = (y0 + y1) + (y2 + y3) + xv[t] * Dvd;
    float sz = zv[t] / (1.f + __expf(-zv[t]));
    yg[(size_t)(mbase + t) * 2048 + d] = f2bf(y * sz);
  }
}

// ---------------- fused head ----------------
__global__ __launch_bounds__(256) void lnlast_gemv1_k(const float* __restrict__ xb,
    const float* __restrict__ fnw, const float* __restrict__ fnb,
    const float* __restrict__ h1w, const float* __restrict__ h1b,
    float* __restrict__ hpre) {
  int blk = blockIdx.x, tid = threadIdx.x;
  int b = blk >> 9;
  int jbase = (blk & 511) * 4;
  int wv = tid >> 6, lane = tid & 63;
  const float* x = xb + (size_t)(b * 1024 + 1023) * 1024;
  float4 v = ((const float4*)x)[tid];
  float s = v.x + v.y + v.z + v.w;
  float q = v.x*v.x + v.y*v.y + v.z*v.z + v.w*v.w;
  for (int o = 32; o; o >>= 1) { s += __shfl_down(s, o); q += __shfl_down(q, o); }
  __shared__ float sb[4], qb[4];
  __shared__ float row[1024];
  if (lane == 0) { sb[wv] = s; qb[wv] = q; }
  __syncthreads();
  s = sb[0] + sb[1] + sb[2] + sb[3];
  q = qb[0] + qb[1] + qb[2] + qb[3];
  float mean = s * (1.f / 1024.f);
  float rstd = rsqrtf(q * (1.f / 1024.f) - mean * mean + 1e-5f);
  float4 wv4 = ((const float4*)fnw)[tid];
  float4 bv4 = ((const float4*)fnb)[tid];
  float4 o;
  o.x = (v.x - mean) * rstd * wv4.x + bv4.x;
  o.y = (v.y - mean) * rstd * wv4.y + bv4.y;
  o.z = (v.z - mean) * rstd * wv4.z + bv4.z;
  o.w = (v.w - mean) * rstd * wv4.w + bv4.w;
  ((float4*)row)[tid] = o;
  __syncthreads();
  int j = jbase + wv;
  const float* w = h1w + (size_t)j * 1024;
  float acc = 0.f;
#pragma unroll
  for (int qq = 0; qq < 4; ++qq) {
    int col = qq * 256 + lane * 4;
    float4 xv = *(const float4*)&row[col];
    float4 wvv = *(const float4*)&w[col];
    acc += xv.x*wvv.x + xv.y*wvv.y + xv.z*wvv.z + xv.w*wvv.w;
  }
  for (int o2 = 32; o2; o2 >>= 1) acc += __shfl_down(acc, o2);
  if (lane == 0) hpre[b * 2048 + j] = acc + h1b[j];
}

__global__ __launch_bounds__(256) void lngelu_gemv2_k(const float* __restrict__ hpre,
    const float* __restrict__ hlnw, const float* __restrict__ hlnb,
    const float* __restrict__ h2w, const float* __restrict__ h2b,
    float* __restrict__ out) {
  int blk = blockIdx.x, tid = threadIdx.x;
  int b = (blk >= 250) ? 1 : 0;
  int jbase = (blk - b * 250) * 4;
  int wv = tid >> 6, lane = tid & 63;
  const float* x = hpre + b * 2048;
  float4 v0 = ((const float4*)x)[tid];
  float4 v1 = ((const float4*)x)[tid + 256];
  float s = v0.x+v0.y+v0.z+v0.w + v1.x+v1.y+v1.z+v1.w;
  float q = v0.x*v0.x+v0.y*v0.y+v0.z*v0.z+v0.w*v0.w
          + v1.x*v1.x+v1.y*v1.y+v1.z*v1.z+v1.w*v1.w;
  for (int o = 32; o; o >>= 1) { s += __shfl_down(s, o); q += __shfl_down(q, o); }
  __shared__ float sb[4], qb[4];
  __shared__ float row[2048];
  if (lane == 0) { sb[wv] = s; qb[wv] = q; }
  __syncthreads();
  s = sb[0] + sb[1] + sb[2] + sb[3];
  q = qb[0] + qb[1] + qb[2] + qb[3];
  float mean = s * (1.f / 2048.f);
  float rstd = rsqrtf(q * (1.f / 2048.f) - mean * mean + 1e-5f);
#pragma unroll
  for (int h = 0; h < 2; ++h) {
    float4 v = h ? v1 : v0;
    int c0 = tid * 4 + h * 1024;
    float4 wv4 = *(const float4*)&hlnw[c0];
    float4 bv4 = *(const float4*)&hlnb[c0];
    float4 g;
    g.x = (v.x - mean) * rstd * wv4.x + bv4.x;
    g.y = (v.y - mean) * rstd * wv4.y + bv4.y;
    g.z = (v.z - mean) * rstd * wv4.z + bv4.z;
    g.w = (v.w - mean) * rstd * wv4.w + bv4.w;
    g.x = 0.5f * g.x * (1.f + erff(g.x * 0.70710678f));
    g.y = 0.5f * g.y * (1.f + erff(g.y * 0.70710678f));
    g.z = 0.5f * g.z * (1.f + erff(g.z * 0.70710678f));
    g.w = 0.5f * g.w * (1.f + erff(g.w * 0.70710678f));
    *(float4*)&row[c0] = g;
  }
  __syncthreads();
  int j = jbase + wv;
  const float* w = h2w + (size_t)j * 2048;
  float acc = 0.f;
#pragma unroll
  for (int qq = 0; qq < 8; ++qq) {
    int col = qq * 256 + lane * 4;
    float4 xv = *(const float4*)&row[col];
    float4 wvv = *(const float4*)&w[col];
    acc += xv.x*wvv.x + xv.y*wvv.y + xv.z*wvv.z + xv.w*wvv.w;
  }
  for (int o2 = 32; o2; o2 >>= 1) acc += __shfl_down(acc, o2);
  if (lane == 0) out[b * 1000 + j] = acc + h2b[j];
}

// ---------------- launch ----------------
extern "C" void kernel_launch(void* const* d_in, const int* in_sizes, int n_in,
                              void* d_out, int out_size, void* d_ws, size_t ws_size,
                              hipStream_t stream) {
  const float* x_in = (const float*)d_in[0];
  const float* lnw  = (const float*)d_in[1];
  const float* lnb  = (const float*)d_in[2];
  const float* ipw  = (const float*)d_in[3];
  const float* cw   = (const float*)d_in[4];
  const float* cb   = (const float*)d_in[5];
  const float* xpw  = (const float*)d_in[6];
  const float* dpw  = (const float*)d_in[7];
  const float* dpb  = (const float*)d_in[8];
  const float* Alog = (const float*)d_in[9];
  const float* Dv   = (const float*)d_in[10];
  const float* opw  = (const float*)d_in[11];
  const float* fnw  = (const float*)d_in[12];
  const float* fnb  = (const float*)d_in[13];
  const float* h1w  = (const float*)d_in[14];
  const float* h1b  = (const float*)d_in[15];
  const float* hlnw = (const float*)d_in[16];
  const float* hlnb = (const float*)d_in[17];
  const float* h2w  = (const float*)d_in[18];
  const float* h2b  = (const float*)d_in[19];
  float* out = (float*)d_out;

  char* ws = (char*)d_ws;
  size_t off = 0;
  auto alloc = [&](size_t bytes) -> void* {
    void* p = ws + off; off += (bytes + 255) & ~(size_t)255; return p;
  };
  float* x_buf   = (float*)alloc((size_t)MTOK * DMODEL * 4);
  u16*   xn_bf   = (u16*)  alloc((size_t)MTOK * DMODEL * 2);
  u16*   xz_bf   = (u16*)  alloc((size_t)MTOK * 2 * DINNER * 2);
  u16*   xs_bf   = (u16*)  alloc((size_t)MTOK * DINNER * 2);
  float* xpart   = (float*)alloc((size_t)XPK * MTOK * 128 * 4);
  float* xdbl_l  = (float*)alloc((size_t)MTOK * 128 * 4);
  u16*   dtb     = (u16*)  alloc((size_t)MTOK * DINNER * 2);
  u16*   yg_bf   = (u16*)  alloc((size_t)MTOK * DINNER * 2);
  u16*   w_ip4   = (u16*)  alloc((size_t)NLAYER * 2 * DINNER * DMODEL * 2);
  u16*   w_xp4   = (u16*)  alloc((size_t)NLAYER * 128 * DINNER * 2);
  u16*   w_dt4   = (u16*)  alloc((size_t)NLAYER * DINNER * DTRANK * 2);
  u16*   w_op4   = (u16*)  alloc((size_t)NLAYER * DMODEL * DINNER * 2);
  float* PS_S    = (float*)alloc((size_t)NBATCH * NCH * 16 * 2048 * 4);
  float* sumdt_a = (float*)alloc((size_t)NBATCH * NCH * 2048 * 4);
  u16*   Hb      = (u16*)  alloc((size_t)NBATCH * NCH * 16 * 2048 * 2);
  float* hpre    = (float*)alloc(2 * 2048 * 4);

  hipMemcpyAsync(x_buf, x_in, (size_t)MTOK * DMODEL * 4, hipMemcpyDeviceToDevice, stream);
  { dim3 g(4096, 4); f32_to_bf16_l<<<g, 256, 0, stream>>>(ipw, w_ip4, 2 * DINNER * DMODEL); }
  { dim3 g(256, 4);  cvt_pad_xproj_l<<<g, 256, 0, stream>>>(xpw, w_xp4); }
  { dim3 g(128, 4);  f32_to_bf16_l<<<g, 256, 0, stream>>>(dpw, w_dt4, DINNER * DTRANK); }
  { dim3 g(2048, 4); f32_to_bf16_l<<<g, 256, 0, stream>>>(opw, w_op4, DMODEL * DINNER); }

  for (int i = 0; i < NLAYER; ++i) {
    ln_to_bf16_k<<<MTOK, 256, 0, stream>>>(x_buf, lnw + i * DMODEL, lnb + i * DMODEL, xn_bf);
    gemm_bt<1, 1><<<dim3(512, 1, 1), 512, 0, stream>>>(
        xn_bf, w_ip4 + (size_t)i * 2 * DINNER * DMODEL, (float*)xz_bf,
        1024, 1024, 4096, 1024, 16, 0);
    conv_silu_k<<<2048, 256, 0, stream>>>(xz_bf, cw + (size_t)i * DINNER * 4, cb + i * DINNER, xs_bf);
    { dim3 g(16, 1, XPK);
      gemm_bt<0, 0><<<g, 512, 0, stream>>>(xs_bf, w_xp4 + (size_t)i * 128 * DINNER,
                                           xpart, 2048, 2048, 128, 128, 16, MTOK * 128); }
    reduce_xdbl_k<<<256, 256, 0, stream>>>(xpart, xdbl_l);
    { dim3 g(16, 16, 1);
      gemm_dt_k<<<g, 256, 0, stream>>>(xdbl_l, w_dt4 + (size_t)i * DINNER * DTRANK,
                                       dpb + i * DINNER, dtb); }
    scan_part1<<<1024, 256, 0, stream>>>(dtb, xs_bf, xdbl_l,
                                         Alog + (size_t)i * DINNER * DSTATE, PS_S, sumdt_a);
    scan_prefix<<<256, 256, 0, stream>>>(PS_S, sumdt_a, Alog + (size_t)i * DINNER * DSTATE, Hb);
    scan_part2<<<1024, 256, 0, stream>>>(dtb, xs_bf, xdbl_l, Alog + (size_t)i * DINNER * DSTATE,
                                         Dv + i * DINNER, xz_bf, Hb, yg_bf);
    gemm_bt<3, 1><<<dim3(128, 1, 2), 512, 0, stream>>>(
        yg_bf, w_op4 + (size_t)i * DMODEL * DINNER, x_buf,
        2048, 2048, 1024, 1024, 16, 0);
  }
  lnlast_gemv1_k<<<1024, 256, 0, stream>>>(x_buf, fnw, fnb, h1w, h1b, hpre);
  lngelu_gemv2_k<<<500, 256, 0, stream>>>(hpre, hlnw, hlnb, h2w, h2b, out);
  (void)in_sizes; (void)n_in; (void)out_size; (void)ws_size;
}